// Round 15
// baseline (330.265 us; speedup 1.0000x reference)
//
#include <hip/hip_runtime.h>
#include <hip/hip_bf16.h>

typedef __attribute__((ext_vector_type(8))) __bf16 bf16x8;
typedef __attribute__((ext_vector_type(4))) float f32x4;

// ws layout (shorts):
//  [0, 131072)        per-head weight blobs: 8 heads x 16384 shorts (32 KB)
//                     head blob = 32 sets x 512 shorts; set s, lane l, elem e:
//                       s<16 : Wp2[kc*32+grp*8+e][h*32+nt*16+l15], kc=s>>1, nt=s&1
//                       16-23: Wk [...]                            kc=(s-16)>>1
//                       24-31: Wv [...]                            kc=(s-24)>>1
//                     PE-half = sets 0..15 (16 KB), KV-half = sets 16..31 (16 KB)
//  [131072, 163840)   WqT [256][128]
//  [163840, 229376)   WoT [256][256]
//  [229376, 262144)   WrT [256][128]
#define OFF_BLOB 0
#define OFF_WQ   131072
#define OFF_WO   163840
#define OFF_WR   229376

__device__ __forceinline__ f32x4 mfma16(bf16x8 a, bf16x8 b, f32x4 c) {
    return __builtin_amdgcn_mfma_f32_16x16x32_bf16(a, b, c, 0, 0, 0);
}
__device__ __forceinline__ bf16x8 ldb16(const short* p) { return *(const bf16x8*)p; }

union BfBits { __bf16 b; short s; };
__device__ __forceinline__ short f2b(float x) { BfBits u; u.b = (__bf16)x; return u.s; }
__device__ __forceinline__ float b2f(short x) { BfBits u; u.s = x; return (float)u.b; }

__device__ __forceinline__ void gload_lds16(const short* g, short* l) {
    __builtin_amdgcn_global_load_lds(
        (const __attribute__((address_space(1))) unsigned int*)g,
        (__attribute__((address_space(3))) unsigned int*)l, 16, 0, 0);
}

__global__ void prep_kernel(const float* __restrict__ Wq, const float* __restrict__ Wk,
                            const float* __restrict__ Wv, const float* __restrict__ Wp2,
                            const float* __restrict__ Wo, const float* __restrict__ Wr,
                            short* __restrict__ o) {
    int t = blockIdx.x * 256 + threadIdx.x;
    float v;
    if (t < 131072) {           // per-head fragment blobs
        int h = t >> 14, r = t & 16383, set = r >> 9, li = r & 511;
        int lane = li >> 3, e = li & 7;
        int l15 = lane & 15, grp = lane >> 4;
        const float* src; int kc;
        if (set < 16)      { src = Wp2; kc = set >> 1; }
        else if (set < 24) { src = Wk;  kc = (set - 16) >> 1; }
        else               { src = Wv;  kc = (set - 24) >> 1; }
        int nt = set & 1;
        int n = h * 32 + nt * 16 + l15;
        int k = kc * 32 + grp * 8 + e;
        v = src[k * 256 + n];
    } else if (t < 163840) {    // WqT
        int i = t - 131072, n = i >> 7, k = i & 127;
        v = Wq[k * 256 + n];
    } else if (t < 229376) {    // WoT
        int i = t - 163840, n = i >> 8, k = i & 255;
        v = Wo[k * 256 + n];
    } else {                    // WrT
        int i = t - 229376, n = i >> 7, k = i & 127;
        v = Wr[k * 256 + n];
    }
    o[t] = f2b(v);
}

// 4 waves x 2 m-tiles = 8 centers / 128 rows per block, grid 2048.
// Empirical cap law (R3/4/5/11/13/14): arch-VGPR cap = 256/min_waves.
// (256,2) -> cap 128. The hot loop fits (~116 arch); R14's marginal spill came
// from the phase-4 epilogue peak (aof 32 + xcf 16 + acc) — streamed here so the
// whole kernel fits 128. Goal: TWO independent 4-wave blocks/CU (two barrier
// domains) so one block's softmax overlaps the other's MFMA runs.
__global__ __launch_bounds__(256, 2) void fused_kernel(
    const float* __restrict__ cxyz, const float* __restrict__ cfeat,
    const float* __restrict__ nxyz, const float* __restrict__ nfeat,
    const float* __restrict__ bq,  const float* __restrict__ bk,
    const float* __restrict__ bv,  const float* __restrict__ Wp1,
    const float* __restrict__ bp1, const float* __restrict__ bp2,
    const float* __restrict__ bo,  const float* __restrict__ br,
    const short* __restrict__ wsb, float* __restrict__ out)
{
    __shared__ short sX[8192];          // PE-half weights (16 KB)
    __shared__ short sY[8192];          // KV-half weights (16 KB)
    __shared__ short sQh[8][256];       // q / sqrt(D), bf16 bits (4 KB)
    __shared__ short sAOh[8][256];      // attn_out, bf16 bits (4 KB)
    __shared__ float sBkv[256], sBvv[256];
    __shared__ float sNx[384];
    __shared__ float sCx[24];
    // sWp1b aliases sY (dead after phase 1; first DMA write into sY is the
    // KV-0 prefetch issued after the phase-2 barrier). Stride 9 floats breaks
    // the stride-8 8-way bank conflict. 256*9*4 = 9216 B fits the 16 KB.
    float* sWp1b = (float*)sY;

    const int t = threadIdx.x;
    const int bid = blockIdx.x;
    const int w = t >> 6, lane = t & 63, grp = lane >> 4, l15 = lane & 15;

    // issue one 16 KB half-head blob: 16 sets x 512 shorts; 4 loads per wave.
    auto issue_pe = [&](int h) {
        const short* src = wsb + OFF_BLOB + h * 16384;
        #pragma unroll
        for (int i = 0; i < 4; ++i) {
            int s = w * 4 + i;
            gload_lds16(src + s * 512 + lane * 8, &sX[s * 512]);
        }
    };
    auto issue_kv = [&](int h) {
        const short* src = wsb + OFF_BLOB + h * 16384 + 8192;
        #pragma unroll
        for (int i = 0; i < 4; ++i) {
            int s = w * 4 + i;
            gload_lds16(src + s * 512 + lane * 8, &sY[s * 512]);
        }
    };

    // -------- prologue: async prefetch PE-half of head 0 into sX --------
    issue_pe(0);

    // ---------------- phase 0: staging ----------------
    {
        float p2 = bp2[t];
        sBkv[t] = bk[t] + p2;
        sBvv[t] = bv[t] + p2;
        sWp1b[t*9+0] = Wp1[t];
        sWp1b[t*9+1] = Wp1[256 + t];
        sWp1b[t*9+2] = Wp1[512 + t];
        sWp1b[t*9+3] = Wp1[768 + t];
        sWp1b[t*9+4] = bp1[t];
        sNx[t] = nxyz[bid * 384 + t];
        if (t < 128) sNx[256 + t] = nxyz[bid * 384 + 256 + t];
        if (t < 24)  sCx[t] = cxyz[bid * 24 + t];
    }
    __syncthreads();

    // ---------------- phase 1: per-lane A-fragments (reused all heads) ----
    float pin[2][4];
    #pragma unroll
    for (int mt = 0; mt < 2; ++mt) {
        int row = w*32 + mt*16 + l15;
        int cl = row >> 4;                // == 2*w + mt
        float rx = sNx[row*3+0] - sCx[cl*3+0];
        float ry = sNx[row*3+1] - sCx[cl*3+1];
        float rz = sNx[row*3+2] - sCx[cl*3+2];
        pin[mt][0] = rx; pin[mt][1] = ry; pin[mt][2] = rz;
        pin[mt][3] = sqrtf(rx*rx + ry*ry + rz*rz);
    }

    bf16x8 h1f[2][8];  // relu(pos_in @ Wp1 + bp1) as MFMA A-fragments
    #pragma unroll
    for (int kc = 0; kc < 8; ++kc) {
        bf16x8 f0, f1;
        #pragma unroll
        for (int e = 0; e < 8; ++e) {
            const float* wp = &sWp1b[(kc*32 + grp*8 + e) * 9];
            float w0 = wp[0], w1 = wp[1], w2 = wp[2], w3 = wp[3], bb = wp[4];
            float a = fmaf(pin[0][0],w0, fmaf(pin[0][1],w1, fmaf(pin[0][2],w2, fmaf(pin[0][3],w3, bb))));
            float b = fmaf(pin[1][0],w0, fmaf(pin[1][1],w1, fmaf(pin[1][2],w2, fmaf(pin[1][3],w3, bb))));
            f0[e] = (__bf16)fmaxf(a, 0.f);
            f1[e] = (__bf16)fmaxf(b, 0.f);
        }
        h1f[0][kc] = f0; h1f[1][kc] = f1;
    }

    // neigh_feat fragments (each neighbor row read exactly once from HBM)
    bf16x8 xnf[2][4];
    #pragma unroll
    for (int mt = 0; mt < 2; ++mt) {
        int grow = bid*128 + w*32 + mt*16 + l15;
        const float* pbase = nfeat + grow*128 + grp*8;
        #pragma unroll
        for (int kc = 0; kc < 4; ++kc) {
            const float* p = pbase + kc*32;
            f32x4 a = *(const f32x4*)p;
            f32x4 c = *(const f32x4*)(p + 4);
            bf16x8 v;
            v[0]=(__bf16)a[0]; v[1]=(__bf16)a[1]; v[2]=(__bf16)a[2]; v[3]=(__bf16)a[3];
            v[4]=(__bf16)c[0]; v[5]=(__bf16)c[1]; v[6]=(__bf16)c[2]; v[7]=(__bf16)c[3];
            xnf[mt][kc] = v;
        }
    }

    // ---------------- phase 2: q = (cf @ Wq + bq) / sqrt(D) -> sQh ----------------
    // Streamed: xcf fragment loaded per (ntl,kc) -> low register peak.
    {
        const short* wqT = wsb + OFF_WQ;
        int gc = bid*8 + (l15 & 7);
        float msk = (l15 < 8) ? 1.f : 0.f;
        const float* pbase = cfeat + gc*128 + grp*8;
        #pragma unroll
        for (int ntl = 0; ntl < 4; ++ntl) {
            int n = (w*4 + ntl)*16 + l15;
            f32x4 acc = {0.f, 0.f, 0.f, 0.f};
            #pragma unroll
            for (int kc = 0; kc < 4; ++kc) {
                const float* p = pbase + kc*32;
                f32x4 a = *(const f32x4*)p;
                f32x4 c = *(const f32x4*)(p + 4);
                bf16x8 v;
                v[0]=(__bf16)(a[0]*msk); v[1]=(__bf16)(a[1]*msk); v[2]=(__bf16)(a[2]*msk); v[3]=(__bf16)(a[3]*msk);
                v[4]=(__bf16)(c[0]*msk); v[5]=(__bf16)(c[1]*msk); v[6]=(__bf16)(c[2]*msk); v[7]=(__bf16)(c[3]*msk);
                acc = mfma16(v, ldb16(wqT + n*128 + kc*32 + grp*8), acc);
            }
            float bqn = bq[n];
            #pragma unroll
            for (int r = 0; r < 4; ++r) {
                int m = grp*4 + r;
                if (m < 8) sQh[m][n] = f2b((acc[r] + bqn) * 0.1767766952966369f);
            }
        }
    }
    __syncthreads();   // sQh visible; sWp1b dead; PE-0 prefetch drained

    // issue KV-half of head 0 into sY (alias now dead for all waves)
    issue_kv(0);

    // ---------------- phase 3: half-head pipelined attention ----------------
    #pragma unroll 1
    for (int h = 0; h < 8; ++h) {
        const int hb = h * 32;

        // ---- PE (reads sX) ----
        f32x4 pe[2][2];
        {
            f32x4 z = {0.f, 0.f, 0.f, 0.f};
            pe[0][0]=z; pe[0][1]=z; pe[1][0]=z; pe[1][1]=z;
        }
        #pragma unroll
        for (int kc = 0; kc < 8; ++kc) {
            #pragma unroll
            for (int nt = 0; nt < 2; ++nt) {
                bf16x8 bw = ldb16(sX + (kc*2 + nt)*512 + lane*8);
                pe[0][nt] = mfma16(h1f[0][kc], bw, pe[0][nt]);
                pe[1][nt] = mfma16(h1f[1][kc], bw, pe[1][nt]);
            }
        }
        __syncthreads();              // sX consumed; KV-h (issued 1 phase ago) drained
        if (h < 7) issue_pe(h + 1);   // prefetch PE-half of next head into sX

        // ---- K phase only (ka dead before va lives: peak accums 32) ----
        f32x4 ka[2][2];
        ka[0][0]=pe[0][0]; ka[0][1]=pe[0][1]; ka[1][0]=pe[1][0]; ka[1][1]=pe[1][1];
        #pragma unroll
        for (int kc = 0; kc < 4; ++kc) {
            #pragma unroll
            for (int nt = 0; nt < 2; ++nt) {
                bf16x8 wk8 = ldb16(sY + (kc*2 + nt)*512 + lane*8);
                #pragma unroll
                for (int mt = 0; mt < 2; ++mt)
                    ka[mt][nt] = mfma16(xnf[mt][kc], wk8, ka[mt][nt]);
            }
        }

        // ---- scores + softmax (no max-sub: shift-invariant, scores ~N(0,2)) ----
        float bkv0 = sBkv[hb + l15], bkv1 = sBkv[hb + 16 + l15];
        float p[2][4];
        #pragma unroll
        for (int mt = 0; mt < 2; ++mt) {
            float q0 = b2f(sQh[2*w + mt][hb + l15]);
            float q1 = b2f(sQh[2*w + mt][hb + 16 + l15]);
            float sp[4];
            #pragma unroll
            for (int r = 0; r < 4; ++r)
                sp[r] = q0*(ka[mt][0][r] + bkv0) + q1*(ka[mt][1][r] + bkv1);
            #pragma unroll
            for (int msk = 1; msk < 16; msk <<= 1) {
                sp[0] += __shfl_xor(sp[0], msk);
                sp[1] += __shfl_xor(sp[1], msk);
                sp[2] += __shfl_xor(sp[2], msk);
                sp[3] += __shfl_xor(sp[3], msk);
            }
            const float l2e = 1.4426950408889634f;
            float p0 = exp2f(sp[0]*l2e);
            float p1 = exp2f(sp[1]*l2e);
            float p2 = exp2f(sp[2]*l2e);
            float p3 = exp2f(sp[3]*l2e);
            float sm = (p0+p1) + (p2+p3);
            sm += __shfl_xor(sm, 16);
            sm += __shfl_xor(sm, 32);
            float inv = 1.0f / sm;
            p[mt][0] = p0*inv; p[mt][1] = p1*inv; p[mt][2] = p2*inv; p[mt][3] = p3*inv;
        }

        // ---- V phase (va re-inits from pe; ka is dead) ----
        f32x4 va[2][2];
        va[0][0]=pe[0][0]; va[0][1]=pe[0][1]; va[1][0]=pe[1][0]; va[1][1]=pe[1][1];
        #pragma unroll
        for (int kc = 0; kc < 4; ++kc) {
            #pragma unroll
            for (int nt = 0; nt < 2; ++nt) {
                bf16x8 wv8 = ldb16(sY + (8 + kc*2 + nt)*512 + lane*8);
                #pragma unroll
                for (int mt = 0; mt < 2; ++mt)
                    va[mt][nt] = mfma16(xnf[mt][kc], wv8, va[mt][nt]);
            }
        }

        // ---- PV -> sAOh ----
        float bvv0 = sBvv[hb + l15], bvv1 = sBvv[hb + 16 + l15];
        #pragma unroll
        for (int mt = 0; mt < 2; ++mt) {
            #pragma unroll
            for (int nt = 0; nt < 2; ++nt) {
                float ov = p[mt][0]*va[mt][nt][0] + p[mt][1]*va[mt][nt][1]
                         + p[mt][2]*va[mt][nt][2] + p[mt][3]*va[mt][nt][3];
                ov += __shfl_xor(ov, 16);
                ov += __shfl_xor(ov, 32);
                if (grp == 0) sAOh[2*w + mt][hb + nt*16 + l15] = f2b(ov + (nt ? bvv1 : bvv0));
            }
        }
        __syncthreads();              // sY consumed; PE(h+1) (issued 1 phase ago) drained
        if (h < 7) issue_kv(h + 1);   // prefetch KV-half of next head into sY
    }
    __syncthreads();   // sAOh rows visible across waves for phase 4

    // ---------------- phase 4: out = leaky(AO@Wo + cf@Wr + bo + br) ----------------
    // Streamed fragments: aof/xcf loaded inside the ntl loop (epilogue register
    // peak ~8 live fragment regs instead of 52 — this was R14's spill source).
    const short* woT = wsb + OFF_WO;
    const short* wrT = wsb + OFF_WR;
    {
        int rr = l15 & 7;
        float msk = (l15 < 8) ? 1.f : 0.f;
        int gc = bid*8 + rr;
        const float* pbase = cfeat + gc*128 + grp*8;
        bf16x8 zv;
        #pragma unroll
        for (int e = 0; e < 8; ++e) zv[e] = (__bf16)0.f;
        #pragma unroll
        for (int ntl = 0; ntl < 4; ++ntl) {
            int n = (w*4 + ntl)*16 + l15;
            f32x4 acc = {0.f, 0.f, 0.f, 0.f};
            #pragma unroll
            for (int kc = 0; kc < 8; ++kc) {
                bf16x8 af = (l15 < 8) ? ldb16(&sAOh[rr][kc*32 + grp*8]) : zv;
                acc = mfma16(af, ldb16(woT + n*256 + kc*32 + grp*8), acc);
            }
            #pragma unroll
            for (int kc = 0; kc < 4; ++kc) {
                const float* pp = pbase + kc*32;
                f32x4 a = *(const f32x4*)pp;
                f32x4 c = *(const f32x4*)(pp + 4);
                bf16x8 v;
                v[0]=(__bf16)(a[0]*msk); v[1]=(__bf16)(a[1]*msk); v[2]=(__bf16)(a[2]*msk); v[3]=(__bf16)(a[3]*msk);
                v[4]=(__bf16)(c[0]*msk); v[5]=(__bf16)(c[1]*msk); v[6]=(__bf16)(c[2]*msk); v[7]=(__bf16)(c[3]*msk);
                acc = mfma16(v, ldb16(wrT + n*128 + kc*32 + grp*8), acc);
            }
            float bb = bo[n] + br[n];
            #pragma unroll
            for (int r = 0; r < 4; ++r) {
                int m = grp*4 + r;
                if (m < 8) {
                    float v = acc[r] + bb;
                    out[(bid*8 + m)*256 + n] = (v >= 0.f) ? v : 0.2f*v;
                }
            }
        }
    }
}

extern "C" void kernel_launch(void* const* d_in, const int* in_sizes, int n_in,
                              void* d_out, int out_size, void* d_ws, size_t ws_size,
                              hipStream_t stream) {
    const float* cxyz  = (const float*)d_in[0];
    const float* cfeat = (const float*)d_in[1];
    const float* nxyz  = (const float*)d_in[2];
    const float* nfeat = (const float*)d_in[3];
    const float* Wq  = (const float*)d_in[4];
    const float* bq  = (const float*)d_in[5];
    const float* Wk  = (const float*)d_in[6];
    const float* bk  = (const float*)d_in[7];
    const float* Wv  = (const float*)d_in[8];
    const float* bv  = (const float*)d_in[9];
    const float* Wp1 = (const float*)d_in[10];
    const float* bp1 = (const float*)d_in[11];
    const float* Wp2 = (const float*)d_in[12];
    const float* bp2 = (const float*)d_in[13];
    const float* Wo  = (const float*)d_in[14];
    const float* bo  = (const float*)d_in[15];
    const float* Wr  = (const float*)d_in[16];
    const float* br  = (const float*)d_in[17];
    short* wsb = (short*)d_ws;

    if (ws_size < 262144 * sizeof(short)) return;

    prep_kernel<<<1024, 256, 0, stream>>>(Wq, Wk, Wv, Wp2, Wo, Wr, wsb);
    fused_kernel<<<2048, 256, 0, stream>>>(cxyz, cfeat, nxyz, nfeat,
        bq, bk, bv, Wp1, bp1, bp2, bo, br, wsb, (float*)d_out);
}

// Round 16
// 176.582 us; speedup vs baseline: 1.8703x; 1.8703x over previous
//
#include <hip/hip_runtime.h>
#include <hip/hip_bf16.h>

typedef __attribute__((ext_vector_type(8))) __bf16 bf16x8;
typedef __attribute__((ext_vector_type(4))) float f32x4;

// ws layout (shorts):
//  [0, 131072)        per-head weight blobs: 8 heads x 16384 shorts (32 KB)
//                     head blob = 32 sets x 512 shorts; set s, lane l, elem e:
//                       s<16 : Wp2[kc*32+grp*8+e][h*32+nt*16+l15], kc=s>>1, nt=s&1
//                       16-23: Wk [...]                            kc=(s-16)>>1
//                       24-31: Wv [...]                            kc=(s-24)>>1
//  [131072, 163840)   WqT [256][128]
//  [163840, 229376)   WoT [256][256]
//  [229376, 262144)   WrT [256][128]
#define OFF_BLOB 0
#define OFF_WQ   131072
#define OFF_WO   163840
#define OFF_WR   229376

__device__ __forceinline__ f32x4 mfma16(bf16x8 a, bf16x8 b, f32x4 c) {
    return __builtin_amdgcn_mfma_f32_16x16x32_bf16(a, b, c, 0, 0, 0);
}
__device__ __forceinline__ bf16x8 ldb16(const short* p) { return *(const bf16x8*)p; }

union BfBits { __bf16 b; short s; };
__device__ __forceinline__ short f2b(float x) { BfBits u; u.b = (__bf16)x; return u.s; }
__device__ __forceinline__ float b2f(short x) { BfBits u; u.s = x; return (float)u.b; }

__device__ __forceinline__ void gload_lds16(const short* g, short* l) {
    __builtin_amdgcn_global_load_lds(
        (const __attribute__((address_space(1))) unsigned int*)g,
        (__attribute__((address_space(3))) unsigned int*)l, 16, 0, 0);
}

__global__ void prep_kernel(const float* __restrict__ Wq, const float* __restrict__ Wk,
                            const float* __restrict__ Wv, const float* __restrict__ Wp2,
                            const float* __restrict__ Wo, const float* __restrict__ Wr,
                            short* __restrict__ o) {
    int t = blockIdx.x * 256 + threadIdx.x;
    float v;
    if (t < 131072) {           // per-head fragment blobs
        int h = t >> 14, r = t & 16383, set = r >> 9, li = r & 511;
        int lane = li >> 3, e = li & 7;
        int l15 = lane & 15, grp = lane >> 4;
        const float* src; int kc;
        if (set < 16)      { src = Wp2; kc = set >> 1; }
        else if (set < 24) { src = Wk;  kc = (set - 16) >> 1; }
        else               { src = Wv;  kc = (set - 24) >> 1; }
        int nt = set & 1;
        int n = h * 32 + nt * 16 + l15;
        int k = kc * 32 + grp * 8 + e;
        v = src[k * 256 + n];
    } else if (t < 163840) {    // WqT
        int i = t - 131072, n = i >> 7, k = i & 127;
        v = Wq[k * 256 + n];
    } else if (t < 229376) {    // WoT
        int i = t - 163840, n = i >> 8, k = i & 255;
        v = Wo[k * 256 + n];
    } else {                    // WrT
        int i = t - 229376, n = i >> 7, k = i & 127;
        v = Wr[k * 256 + n];
    }
    o[t] = f2b(v);
}

// CHAMPION (R12): 8 waves x 2 m-tiles = 16 centers / 256 rows per block,
// grid 1024. (512,2) = cap 256 >= natural (~124 arch + ~32 AGPR) -> spill-free.
// K/V phase split (peak accums 32), softmax without max-sub (shift-invariant;
// scores ~N(0,2)), Wp1 LDS stride 9 (bank-conflict fix).
// Occupancy note: 2 waves/SIMD (one 8-wave block/CU) is this algorithm's
// structural ceiling on this toolchain — 7 attempts (R9-R15) to exceed it via
// smaller blocks / LDS cuts / launch-bounds hints all spilled or regressed
// (empirical cap law: arch-VGPR cap = 256/min_waves, independent of block size).
__global__ __launch_bounds__(512, 2) void fused_kernel(
    const float* __restrict__ cxyz, const float* __restrict__ cfeat,
    const float* __restrict__ nxyz, const float* __restrict__ nfeat,
    const float* __restrict__ bq,  const float* __restrict__ bk,
    const float* __restrict__ bv,  const float* __restrict__ Wp1,
    const float* __restrict__ bp1, const float* __restrict__ bp2,
    const float* __restrict__ bo,  const float* __restrict__ br,
    const short* __restrict__ wsb, float* __restrict__ out)
{
    __shared__ short sWBuf[2][16384];   // 64 KB double-buffered head weights
    __shared__ short sQh[16][256];      // q / sqrt(D), bf16 bits (8 KB)
    __shared__ short sAOh[16][256];     // attn_out, bf16 bits (8 KB)
    __shared__ float sBkv[256], sBvv[256];
    __shared__ float sNx[768];
    __shared__ float sCx[48];
    // sWp1b aliases buf1: dead after phase 1; first DMA write of buf1 (prefetch
    // of head 1) is issued after the phase-2 barrier. Stride 9 floats (36 B)
    // breaks the stride-8 8-way bank conflict.
    float* sWp1b = (float*)&sWBuf[1][0];  // [256*9] floats = 9216 B (fits 32 KB)

    const int t = threadIdx.x;
    const int bid = blockIdx.x;
    const int w = t >> 6, lane = t & 63, grp = lane >> 4, l15 = lane & 15;

    // -------- prologue: async prefetch head-0 weights (32 sets) into buf0 ----
    {
        const short* src = wsb + OFF_BLOB;
        #pragma unroll
        for (int i = 0; i < 4; ++i) {
            int s = w * 4 + i;
            gload_lds16(src + s * 512 + lane * 8, &sWBuf[0][s * 512]);
        }
    }

    // ---------------- phase 0: staging ----------------
    {
        if (t < 256) {
            float p2 = bp2[t];
            sBkv[t] = bk[t] + p2;
            sBvv[t] = bv[t] + p2;
            sWp1b[t*9+0] = Wp1[t];
            sWp1b[t*9+1] = Wp1[256 + t];
            sWp1b[t*9+2] = Wp1[512 + t];
            sWp1b[t*9+3] = Wp1[768 + t];
            sWp1b[t*9+4] = bp1[t];
        }
        sNx[t] = nxyz[bid * 768 + t];
        if (t < 256) sNx[512 + t] = nxyz[bid * 768 + 512 + t];
        if (t < 48)  sCx[t] = cxyz[bid * 48 + t];
    }
    __syncthreads();

    // ---------------- phase 1: per-lane A-fragments (reused all heads) ----
    float pin[2][4];
    #pragma unroll
    for (int mt = 0; mt < 2; ++mt) {
        int row = w*32 + mt*16 + l15;
        int cl = row >> 4;                // == 2*w + mt
        float rx = sNx[row*3+0] - sCx[cl*3+0];
        float ry = sNx[row*3+1] - sCx[cl*3+1];
        float rz = sNx[row*3+2] - sCx[cl*3+2];
        pin[mt][0] = rx; pin[mt][1] = ry; pin[mt][2] = rz;
        pin[mt][3] = sqrtf(rx*rx + ry*ry + rz*rz);
    }

    bf16x8 h1f[2][8];  // relu(pos_in @ Wp1 + bp1) as MFMA A-fragments
    #pragma unroll
    for (int kc = 0; kc < 8; ++kc) {
        bf16x8 f0, f1;
        #pragma unroll
        for (int e = 0; e < 8; ++e) {
            const float* wp = &sWp1b[(kc*32 + grp*8 + e) * 9];
            float w0 = wp[0], w1 = wp[1], w2 = wp[2], w3 = wp[3], bb = wp[4];
            float a = fmaf(pin[0][0],w0, fmaf(pin[0][1],w1, fmaf(pin[0][2],w2, fmaf(pin[0][3],w3, bb))));
            float b = fmaf(pin[1][0],w0, fmaf(pin[1][1],w1, fmaf(pin[1][2],w2, fmaf(pin[1][3],w3, bb))));
            f0[e] = (__bf16)fmaxf(a, 0.f);
            f1[e] = (__bf16)fmaxf(b, 0.f);
        }
        h1f[0][kc] = f0; h1f[1][kc] = f1;
    }

    // neigh_feat fragments (each neighbor row read exactly once from HBM)
    bf16x8 xnf[2][4];
    #pragma unroll
    for (int mt = 0; mt < 2; ++mt) {
        int grow = bid*256 + w*32 + mt*16 + l15;
        const float* pbase = nfeat + grow*128 + grp*8;
        #pragma unroll
        for (int kc = 0; kc < 4; ++kc) {
            const float* p = pbase + kc*32;
            f32x4 a = *(const f32x4*)p;
            f32x4 c = *(const f32x4*)(p + 4);
            bf16x8 v;
            v[0]=(__bf16)a[0]; v[1]=(__bf16)a[1]; v[2]=(__bf16)a[2]; v[3]=(__bf16)a[3];
            v[4]=(__bf16)c[0]; v[5]=(__bf16)c[1]; v[6]=(__bf16)c[2]; v[7]=(__bf16)c[3];
            xnf[mt][kc] = v;
        }
    }

    // ---------------- phase 2: q = (cf @ Wq + bq) / sqrt(D) -> sQh ----------------
    {
        bf16x8 xcf[4];
        int gc = bid*16 + l15;
        const float* pbase = cfeat + gc*128 + grp*8;
        #pragma unroll
        for (int kc = 0; kc < 4; ++kc) {
            const float* p = pbase + kc*32;
            f32x4 a = *(const f32x4*)p;
            f32x4 c = *(const f32x4*)(p + 4);
            bf16x8 v;
            v[0]=(__bf16)a[0]; v[1]=(__bf16)a[1]; v[2]=(__bf16)a[2]; v[3]=(__bf16)a[3];
            v[4]=(__bf16)c[0]; v[5]=(__bf16)c[1]; v[6]=(__bf16)c[2]; v[7]=(__bf16)c[3];
            xcf[kc] = v;
        }
        const short* wqT = wsb + OFF_WQ;
        #pragma unroll
        for (int ntl = 0; ntl < 2; ++ntl) {
            int n = (w*2 + ntl)*16 + l15;
            f32x4 acc = {0.f, 0.f, 0.f, 0.f};
            #pragma unroll
            for (int kc = 0; kc < 4; ++kc)
                acc = mfma16(xcf[kc], ldb16(wqT + n*128 + kc*32 + grp*8), acc);
            float bqn = bq[n];
            #pragma unroll
            for (int r = 0; r < 4; ++r) {
                int m = grp*4 + r;
                sQh[m][n] = f2b((acc[r] + bqn) * 0.1767766952966369f);
            }
        }
    }
    __syncthreads();   // sQh visible; sWp1b dead; head-0 prefetch drained

    // ---------------- phase 3: pipelined per-head attention ----------------
    #pragma unroll 1
    for (int h = 0; h < 8; ++h) {
        const short* cw = sWBuf[h & 1];
        if (h < 7) {   // prefetch next head into the other buffer
            short* dst = sWBuf[(h + 1) & 1];
            const short* src = wsb + OFF_BLOB + (h + 1) * 16384;
            #pragma unroll
            for (int i = 0; i < 4; ++i) {
                int s = w * 4 + i;
                gload_lds16(src + s * 512 + lane * 8, dst + s * 512);
            }
        }
        const int hb = h * 32;

        // ---- PE (Wp2 head-slice) ----
        f32x4 pe[2][2];
        {
            f32x4 z = {0.f, 0.f, 0.f, 0.f};
            pe[0][0]=z; pe[0][1]=z; pe[1][0]=z; pe[1][1]=z;
        }
        #pragma unroll
        for (int kc = 0; kc < 8; ++kc) {
            #pragma unroll
            for (int nt = 0; nt < 2; ++nt) {
                bf16x8 bw = ldb16(cw + (kc*2 + nt)*512 + lane*8);
                pe[0][nt] = mfma16(h1f[0][kc], bw, pe[0][nt]);
                pe[1][nt] = mfma16(h1f[1][kc], bw, pe[1][nt]);
            }
        }

        // ---- K phase only (ka dead before va lives: peak accums 32 not 48) ----
        f32x4 ka[2][2];
        ka[0][0]=pe[0][0]; ka[0][1]=pe[0][1]; ka[1][0]=pe[1][0]; ka[1][1]=pe[1][1];
        #pragma unroll
        for (int kc = 0; kc < 4; ++kc) {
            #pragma unroll
            for (int nt = 0; nt < 2; ++nt) {
                bf16x8 wk8 = ldb16(cw + (16 + kc*2 + nt)*512 + lane*8);
                #pragma unroll
                for (int mt = 0; mt < 2; ++mt)
                    ka[mt][nt] = mfma16(xnf[mt][kc], wk8, ka[mt][nt]);
            }
        }

        // ---- scores + softmax (no max-sub: shift-invariant, scores ~N(0,2)) ----
        float bkv0 = sBkv[hb + l15], bkv1 = sBkv[hb + 16 + l15];
        float p[2][4];
        #pragma unroll
        for (int mt = 0; mt < 2; ++mt) {
            float q0 = b2f(sQh[2*w + mt][hb + l15]);
            float q1 = b2f(sQh[2*w + mt][hb + 16 + l15]);
            float sp[4];
            #pragma unroll
            for (int r = 0; r < 4; ++r)
                sp[r] = q0*(ka[mt][0][r] + bkv0) + q1*(ka[mt][1][r] + bkv1);
            #pragma unroll
            for (int msk = 1; msk < 16; msk <<= 1) {
                sp[0] += __shfl_xor(sp[0], msk);
                sp[1] += __shfl_xor(sp[1], msk);
                sp[2] += __shfl_xor(sp[2], msk);
                sp[3] += __shfl_xor(sp[3], msk);
            }
            const float l2e = 1.4426950408889634f;
            float p0 = exp2f(sp[0]*l2e);
            float p1 = exp2f(sp[1]*l2e);
            float p2 = exp2f(sp[2]*l2e);
            float p3 = exp2f(sp[3]*l2e);
            float sm = (p0+p1) + (p2+p3);
            sm += __shfl_xor(sm, 16);
            sm += __shfl_xor(sm, 32);
            float inv = 1.0f / sm;
            p[mt][0] = p0*inv; p[mt][1] = p1*inv; p[mt][2] = p2*inv; p[mt][3] = p3*inv;
        }

        // ---- V phase (va re-inits from pe; ka is dead) ----
        f32x4 va[2][2];
        va[0][0]=pe[0][0]; va[0][1]=pe[0][1]; va[1][0]=pe[1][0]; va[1][1]=pe[1][1];
        #pragma unroll
        for (int kc = 0; kc < 4; ++kc) {
            #pragma unroll
            for (int nt = 0; nt < 2; ++nt) {
                bf16x8 wv8 = ldb16(cw + (24 + kc*2 + nt)*512 + lane*8);
                #pragma unroll
                for (int mt = 0; mt < 2; ++mt)
                    va[mt][nt] = mfma16(xnf[mt][kc], wv8, va[mt][nt]);
            }
        }

        // ---- PV -> sAOh ----
        float bvv0 = sBvv[hb + l15], bvv1 = sBvv[hb + 16 + l15];
        #pragma unroll
        for (int mt = 0; mt < 2; ++mt) {
            #pragma unroll
            for (int nt = 0; nt < 2; ++nt) {
                float ov = p[mt][0]*va[mt][nt][0] + p[mt][1]*va[mt][nt][1]
                         + p[mt][2]*va[mt][nt][2] + p[mt][3]*va[mt][nt][3];
                ov += __shfl_xor(ov, 16);
                ov += __shfl_xor(ov, 32);
                if (grp == 0) sAOh[2*w + mt][hb + nt*16 + l15] = f2b(ov + (nt ? bvv1 : bvv0));
            }
        }
        __syncthreads();  // buf[h&1] fully read; prefetch h+1 drained
    }

    // ---------------- phase 4: out = leaky(AO@Wo + cf@Wr + bo + br) ----------------
    const short* woT = wsb + OFF_WO;
    const short* wrT = wsb + OFF_WR;
    bf16x8 aof[8];
    #pragma unroll
    for (int kc = 0; kc < 8; ++kc)
        aof[kc] = ldb16(&sAOh[l15][kc*32 + grp*8]);
    bf16x8 xcf[4];
    {
        int gc = bid*16 + l15;
        const float* pbase = cfeat + gc*128 + grp*8;
        #pragma unroll
        for (int kc = 0; kc < 4; ++kc) {
            const float* p = pbase + kc*32;
            f32x4 a = *(const f32x4*)p;
            f32x4 c = *(const f32x4*)(p + 4);
            bf16x8 v;
            v[0]=(__bf16)a[0]; v[1]=(__bf16)a[1]; v[2]=(__bf16)a[2]; v[3]=(__bf16)a[3];
            v[4]=(__bf16)c[0]; v[5]=(__bf16)c[1]; v[6]=(__bf16)c[2]; v[7]=(__bf16)c[3];
            xcf[kc] = v;
        }
    }
    #pragma unroll
    for (int ntl = 0; ntl < 2; ++ntl) {
        int n = (w*2 + ntl)*16 + l15;
        f32x4 acc = {0.f, 0.f, 0.f, 0.f};
        #pragma unroll
        for (int kc = 0; kc < 8; ++kc)
            acc = mfma16(aof[kc], ldb16(woT + n*256 + kc*32 + grp*8), acc);
        #pragma unroll
        for (int kc = 0; kc < 4; ++kc)
            acc = mfma16(xcf[kc], ldb16(wrT + n*128 + kc*32 + grp*8), acc);
        float bb = bo[n] + br[n];
        #pragma unroll
        for (int r = 0; r < 4; ++r) {
            int m = grp*4 + r;
            float v = acc[r] + bb;
            out[(bid*16 + m)*256 + n] = (v >= 0.f) ? v : 0.2f*v;
        }
    }
}

extern "C" void kernel_launch(void* const* d_in, const int* in_sizes, int n_in,
                              void* d_out, int out_size, void* d_ws, size_t ws_size,
                              hipStream_t stream) {
    const float* cxyz  = (const float*)d_in[0];
    const float* cfeat = (const float*)d_in[1];
    const float* nxyz  = (const float*)d_in[2];
    const float* nfeat = (const float*)d_in[3];
    const float* Wq  = (const float*)d_in[4];
    const float* bq  = (const float*)d_in[5];
    const float* Wk  = (const float*)d_in[6];
    const float* bk  = (const float*)d_in[7];
    const float* Wv  = (const float*)d_in[8];
    const float* bv  = (const float*)d_in[9];
    const float* Wp1 = (const float*)d_in[10];
    const float* bp1 = (const float*)d_in[11];
    const float* Wp2 = (const float*)d_in[12];
    const float* bp2 = (const float*)d_in[13];
    const float* Wo  = (const float*)d_in[14];
    const float* bo  = (const float*)d_in[15];
    const float* Wr  = (const float*)d_in[16];
    const float* br  = (const float*)d_in[17];
    short* wsb = (short*)d_ws;

    if (ws_size < 262144 * sizeof(short)) return;

    prep_kernel<<<1024, 256, 0, stream>>>(Wq, Wk, Wv, Wp2, Wo, Wr, wsb);
    fused_kernel<<<1024, 512, 0, stream>>>(cxyz, cfeat, nxyz, nfeat,
        bq, bk, bv, Wp1, bp1, bp2, bo, br, wsb, (float*)d_out);
}